// Round 5
// baseline (806.017 us; speedup 1.0000x reference)
//
#include <hip/hip_runtime.h>
#include <hip/hip_bf16.h>

typedef __hip_bfloat16 bf16;
typedef __attribute__((ext_vector_type(8))) short bf16x8;
typedef __attribute__((ext_vector_type(4))) float f32x4;

#define MFMA16(a, b, c) __builtin_amdgcn_mfma_f32_16x16x32_bf16(a, b, c, 0, 0, 0)

// Problem constants (B=1)
#define HH 256
#define WW 256
#define NHEADS 8
#define NROWS 65536

// ws layout:
//   R0 @ 0          (67108864): width Ow (w-major) -- written by fused width kernel
//   R1 @ 67108864   (67108864): height q2 -> height v
//   R2 @ 134217728  (67108864): height k2 -> Oh (h-major)
//   R3 @ 201326592  (2097152):  Wt (384K) @+0 | P bf16 (1M) @+393216 | Wo_w/Wo_h @+1441792
//   d_out doubles as split-K dots scratch dp (8 x 2MB) before k_outproj overwrites it.
//
// LESSON (R4): never stage producer->consumer data through freshly-written workspace
// when the consumer can re-read the stable kernel INPUT instead -- per-XCD L2 flush +
// invalidate at the kernel boundary made an 8 MB pre-transposed xT cost 1 GB/dispatch
// of fabric traffic. x (16 MB, read-only) stays cache-resident across iterations.
//
// MFMA fragment conventions (verified m89/m91/m120):
//   A-frag: lane l holds A[m = l&15][k = (l>>4)*8 + t], t=0..7
//   B-frag: lane l holds B[n = l&15][k = (l>>4)*8 + t]
//   C/D   : lane l, reg r -> (col = l&15, row = (l>>4)*4 + r)
//   D[m][n] = sum_k A[m][k]*B[n][k]

__device__ __forceinline__ bf16x8 cvt8(const float* f) {
  bf16x8 r;
  bf16* h = (bf16*)&r;
#pragma unroll
  for (int i = 0; i < 8; i++) h[i] = __float2bfloat16(f[i]);
  return r;
}

// ---------------------------------------------------------------- Wq|Wkv transpose -> bf16 [1536][64]
__global__ void __launch_bounds__(256) k_wt1(const float* __restrict__ Wq,
                                             const float* __restrict__ Wkv,
                                             bf16* __restrict__ Wt) {
  const int idx = blockIdx.x * 256 + threadIdx.x;  // [0, 98304)
  const int k = idx / 1536, c = idx - k * 1536;
  const float val = (c < 512) ? Wq[k * 512 + c] : Wkv[k * 1024 + (c - 512)];
  Wt[(size_t)c * 64 + k] = __float2bfloat16(val);
}

// ---------------------------------------------------------------- Wout transpose -> bf16 [64][512]
__global__ void __launch_bounds__(256) k_wo(const float* __restrict__ Wout_w,
                                            const float* __restrict__ Wout_h,
                                            bf16* __restrict__ Wo_w,
                                            bf16* __restrict__ Wo_h) {
  int idx = blockIdx.x * 256 + threadIdx.x;  // [0, 65536)
  const float* W = Wout_w;
  bf16* dst = Wo_w;
  if (idx >= 32768) { idx -= 32768; W = Wout_h; dst = Wo_h; }
  const int c = idx >> 9, d = idx & 511;
  dst[idx] = __float2bfloat16(W[d * 64 + c]);  // Wo[c][d] = Wout[d][c]
}

// ---------------------------------------------------------------- QKV via MFMA (height phase)
__global__ void __launch_bounds__(256) k_qkv_mfma(const float* __restrict__ x,
                                                  const bf16* __restrict__ Wt,
                                                  bf16* __restrict__ d0,
                                                  bf16* __restrict__ d1,
                                                  bf16* __restrict__ d2,
                                                  int swap, int cg_lo, int cg_hi) {
  __shared__ __align__(16) bf16 Cs[64 * 136];  // 17408 B
  const int tid = threadIdx.x, lane = tid & 63, wv = tid >> 6;
  const int m16 = lane & 15, kq = lane >> 4;
  const int rowA = blockIdx.x * 64 + wv * 16 + m16;

  const float* xr = x + (size_t)rowA * 64;
  float xf[8];
  bf16x8 af[2];
  *(float4*)&xf[0] = *(const float4*)(xr + kq * 8);
  *(float4*)&xf[4] = *(const float4*)(xr + kq * 8 + 4);
  af[0] = cvt8(xf);
  *(float4*)&xf[0] = *(const float4*)(xr + 32 + kq * 8);
  *(float4*)&xf[4] = *(const float4*)(xr + 32 + kq * 8 + 4);
  af[1] = cvt8(xf);

  size_t wrow[4];
#pragma unroll
  for (int s = 0; s < 4; s++) {
    const int row = (s * 256 + tid) >> 4;
    const int rc = blockIdx.x * 64 + row;
    const int rr = swap ? (((rc & 255) << 8) | (rc >> 8)) : rc;
    wrow[s] = (size_t)rr * 512;
  }
  const int ccol = (tid & 15) * 8;
  const int lrow0 = wv * 16 + kq * 4;

#pragma unroll 1
  for (int cg = cg_lo; cg < cg_hi; cg++) {
    bf16* dst = (cg < 4) ? d0 : (cg < 8) ? d1 : d2;
    const int cbase = (cg & 3) * 128;
#pragma unroll
    for (int ct = 0; ct < 8; ct++) {
      const bf16* wp = Wt + (size_t)(cg * 128 + ct * 16 + m16) * 64 + kq * 8;
      const bf16x8 b0 = *(const bf16x8*)wp;
      const bf16x8 b1 = *(const bf16x8*)(wp + 32);
      f32x4 a = (f32x4){0.f, 0.f, 0.f, 0.f};
      a = MFMA16(af[0], b0, a);
      a = MFMA16(af[1], b1, a);
#pragma unroll
      for (int r = 0; r < 4; r++)
        Cs[(lrow0 + r) * 136 + ct * 16 + m16] = __float2bfloat16(a[r]);
    }
    __syncthreads();
#pragma unroll
    for (int s = 0; s < 4; s++) {
      const int row = (s * 256 + tid) >> 4;
      *(uint4*)(dst + wrow[s] + cbase + ccol) = *(const uint4*)&Cs[row * 136 + ccol];
    }
    __syncthreads();
  }
}

// ---------------------------------------------------------------- FUSED width QKV + attention
// Block (w, head), 4 waves, reads x (fp32 input, cache-resident) directly.
// LDS 49152 -> 3 blocks/CU:
//   Qs [256][64] granule-XOR-swizzled @0      (32 KB) -> Ps (4x5 KB) overlays after qf load
//   Ks [64][64]  granule-XOR-swizzled @32768  ( 8 KB) -- one 64-row QUARTER at a time
//   Vt [64 d][64 j] granule-XOR-swizzled @40960 (8 KB)
// Swizzle: element (row, c) at row*64 + (((c>>3) ^ (row&7))<<3) + (c&7).
// Quarters g=0..3: KV MFMA -> prefetch next quarter's x rows -> barrier -> attn -> barrier.
// The prefetch retires its ~L2-latency under the attention MFMA phase.
__global__ void __launch_bounds__(256, 3)
k_width_fused(const float* __restrict__ x, const bf16* __restrict__ Wt,
              bf16* __restrict__ Ow) {
  __shared__ __align__(16) char smem[49152];
  bf16* Qs = (bf16*)smem;
  bf16* Ks = (bf16*)(smem + 32768);
  bf16* Vt = (bf16*)(smem + 40960);
  const int w = blockIdx.x, head = blockIdx.y;
  const int tid = threadIdx.x, lane = tid & 63, wv = tid >> 6;
  bf16* Ps = (bf16*)(smem + wv * 5120);  // overlays Qs (dead after qf load)
  const int m16 = lane & 15, kq = lane >> 4;
  const int i0 = wv * 64;

  // ---- Q phase: this wave's 64 rows (i = h), all 64 head-cols ----
  bf16x8 af[4][2];
#pragma unroll
  for (int mt = 0; mt < 4; mt++) {
    const float* xr = x + ((size_t)((i0 + mt * 16 + m16) * 256 + w)) * 64;
    float xf[8];
    *(float4*)&xf[0] = *(const float4*)(xr + kq * 8);
    *(float4*)&xf[4] = *(const float4*)(xr + kq * 8 + 4);
    af[mt][0] = cvt8(xf);
    *(float4*)&xf[0] = *(const float4*)(xr + 32 + kq * 8);
    *(float4*)&xf[4] = *(const float4*)(xr + 32 + kq * 8 + 4);
    af[mt][1] = cvt8(xf);
  }
#pragma unroll
  for (int nt = 0; nt < 4; nt++) {
    const bf16* wp = Wt + (size_t)(head * 64 + nt * 16 + m16) * 64 + kq * 8;
    const bf16x8 w0 = *(const bf16x8*)wp;
    const bf16x8 w1 = *(const bf16x8*)(wp + 32);
#pragma unroll
    for (int mt = 0; mt < 4; mt++) {
      f32x4 a = (f32x4){0.f, 0.f, 0.f, 0.f};
      a = MFMA16(af[mt][0], w0, a);
      a = MFMA16(af[mt][1], w1, a);
#pragma unroll
      for (int r = 0; r < 4; r++) {
        const int i = i0 + mt * 16 + kq * 4 + r;
        const int d = nt * 16 + m16;
        Qs[i * 64 + (((d >> 3) ^ (i & 7)) << 3) + (d & 7)] = __float2bfloat16(a[r]);
      }
    }
  }
  __syncthreads();
  // qf A-frags from own rows (swizzled read, conflict-free)
  bf16x8 qf[4][2];
#pragma unroll
  for (int it = 0; it < 4; it++)
#pragma unroll
    for (int ks = 0; ks < 2; ks++)
      qf[it][ks] = *(const bf16x8*)&Qs[(i0 + it * 16 + m16) * 64 +
                                       (((ks * 4 + kq) ^ (m16 & 7)) << 3)];

  f32x4 acc[4][4];
#pragma unroll
  for (int a = 0; a < 4; a++)
#pragma unroll
    for (int b = 0; b < 4; b++) acc[a][b] = (f32x4){0.f, 0.f, 0.f, 0.f};
  float rsum[4][4];
#pragma unroll
  for (int a = 0; a < 4; a++)
#pragma unroll
    for (int r = 0; r < 4; r++) rsum[a][r] = 0.f;

  // prefetch quarter 0's x rows (this wave computes rows wv*16..+16 of each quarter)
  float xfc[16];
  {
    const float* xr = x + ((size_t)((wv * 16 + m16) * 256 + w)) * 64;
    *(float4*)&xfc[0] = *(const float4*)(xr + kq * 8);
    *(float4*)&xfc[4] = *(const float4*)(xr + kq * 8 + 4);
    *(float4*)&xfc[8] = *(const float4*)(xr + 32 + kq * 8);
    *(float4*)&xfc[12] = *(const float4*)(xr + 32 + kq * 8 + 4);
  }

#pragma unroll 1
  for (int g = 0; g < 4; g++) {
    // ---- K/V quarter: MFMA from prefetched rows ----
    {
      const bf16x8 ak0 = cvt8(&xfc[0]);
      const bf16x8 ak1 = cvt8(&xfc[8]);
#pragma unroll
      for (int nt = 0; nt < 4; nt++) {
        const int d = nt * 16 + m16;
        {  // K -> Ks
          const bf16* wp = Wt + (size_t)(512 + head * 64 + d) * 64 + kq * 8;
          const bf16x8 w0 = *(const bf16x8*)wp;
          const bf16x8 w1 = *(const bf16x8*)(wp + 32);
          f32x4 a = (f32x4){0.f, 0.f, 0.f, 0.f};
          a = MFMA16(ak0, w0, a);
          a = MFMA16(ak1, w1, a);
#pragma unroll
          for (int r = 0; r < 4; r++) {
            const int jl = wv * 16 + kq * 4 + r;  // local row in quarter
            Ks[jl * 64 + (((d >> 3) ^ (jl & 7)) << 3) + (d & 7)] = __float2bfloat16(a[r]);
          }
        }
        {  // V -> Vt (transposed), 4 consecutive j packed 8 B
          const bf16* wp = Wt + (size_t)(1024 + head * 64 + d) * 64 + kq * 8;
          const bf16x8 w0 = *(const bf16x8*)wp;
          const bf16x8 w1 = *(const bf16x8*)(wp + 32);
          f32x4 a = (f32x4){0.f, 0.f, 0.f, 0.f};
          a = MFMA16(ak0, w0, a);
          a = MFMA16(ak1, w1, a);
          const int jb = wv * 16 + kq * 4;
          bf16 tmp[4];
#pragma unroll
          for (int r = 0; r < 4; r++) tmp[r] = __float2bfloat16(a[r]);
          *(uint2*)&Vt[d * 64 + (((jb >> 3) ^ (d & 7)) << 3) + (jb & 7)] =
              *(const uint2*)tmp;
        }
      }
    }
    // issue next quarter's gather NOW; it retires under the attention MFMAs
    float xfn[16];
    if (g < 3) {
      const float* xr = x + ((size_t)(((g + 1) * 64 + wv * 16 + m16) * 256 + w)) * 64;
      *(float4*)&xfn[0] = *(const float4*)(xr + kq * 8);
      *(float4*)&xfn[4] = *(const float4*)(xr + kq * 8 + 4);
      *(float4*)&xfn[8] = *(const float4*)(xr + 32 + kq * 8);
      *(float4*)&xfn[12] = *(const float4*)(xr + 32 + kq * 8 + 4);
    }
    __syncthreads();
    // ---- attention over this quarter's 64 j (2 chunks of 32) ----
#pragma unroll
    for (int jcl = 0; jcl < 2; jcl++) {
      bf16x8 kf[2][2];
#pragma unroll
      for (int jt = 0; jt < 2; jt++) {
        const int j = jcl * 32 + jt * 16 + m16;  // local row in quarter
#pragma unroll
        for (int ks = 0; ks < 2; ks++)
          kf[jt][ks] = *(const bf16x8*)&Ks[j * 64 + (((ks * 4 + kq) ^ (j & 7)) << 3)];
      }
#pragma unroll
      for (int it = 0; it < 4; it++)
#pragma unroll
        for (int jt = 0; jt < 2; jt++) {
          f32x4 s = (f32x4){0.f, 0.f, 0.f, 0.f};
          s = MFMA16(qf[it][0], kf[jt][0], s);
          s = MFMA16(qf[it][1], kf[jt][1], s);
#pragma unroll
          for (int r = 0; r < 4; r++) {
            float p = __expf(s[r] * 0.125f);
            rsum[it][r] += p;
            Ps[(it * 16 + kq * 4 + r) * 40 + jt * 16 + m16] = __float2bfloat16(p);
          }
        }
      bf16x8 pf[4], vf[4];
#pragma unroll
      for (int it = 0; it < 4; it++)
        pf[it] = *(const bf16x8*)&Ps[(it * 16 + m16) * 40 + kq * 8];
#pragma unroll
      for (int dt = 0; dt < 4; dt++)
        vf[dt] = *(const bf16x8*)&Vt[(dt * 16 + m16) * 64 +
                                     (((jcl * 4 + kq) ^ (m16 & 7)) << 3)];
#pragma unroll
      for (int it = 0; it < 4; it++)
#pragma unroll
        for (int dt = 0; dt < 4; dt++) acc[it][dt] = MFMA16(pf[it], vf[dt], acc[it][dt]);
    }
    __syncthreads();
    if (g < 3) {
#pragma unroll
      for (int t = 0; t < 16; t++) xfc[t] = xfn[t];
    }
  }

#pragma unroll
  for (int it = 0; it < 4; it++)
#pragma unroll
    for (int r = 0; r < 4; r++) {
      float s = rsum[it][r];
      s += __shfl_xor(s, 1); s += __shfl_xor(s, 2);
      s += __shfl_xor(s, 4); s += __shfl_xor(s, 8);
      rsum[it][r] = 1.f / s;
    }
#pragma unroll
  for (int it = 0; it < 4; it++)
#pragma unroll
    for (int dt = 0; dt < 4; dt++)
#pragma unroll
      for (int r = 0; r < 4; r++) {
        const int i = i0 + it * 16 + kq * 4 + r;  // = h
        Ow[((size_t)(w * 256 + i)) * 512 + head * 64 + dt * 16 + m16] =
            __float2bfloat16(acc[it][dt][r] * rsum[it][r]);
      }
}

// ---------------------------------------------------------------- height tied dots, split-K, plain stores
__global__ void __launch_bounds__(256, 2)
k_dots_s(const bf16* __restrict__ q, const bf16* __restrict__ kk, float* __restrict__ dp) {
  __shared__ __align__(16) bf16 Qs[64 * 72];
  __shared__ __align__(16) bf16 Ks[64 * 72];
  const int tile = blockIdx.x, head = blockIdx.y, rc = blockIdx.z;
  const int i0 = (tile >> 2) * 64, j0 = (tile & 3) * 64;
  const int tid = threadIdx.x, lane = tid & 63, wv = tid >> 6;
  const int m16 = lane & 15, kq = lane >> 4;
  float* slice = dp + (size_t)rc * 524288 + (size_t)head * 65536;

  f32x4 acc[4];
#pragma unroll
  for (int b = 0; b < 4; b++) acc[b] = (f32x4){0.f, 0.f, 0.f, 0.f};

  const int row = tid >> 2, ch = (tid & 3) * 16;
#pragma unroll 1
  for (int rr = 0; rr < 32; rr++) {
    const int rrow = rc * 32 + rr;
    __syncthreads();
    {
      const bf16* qsrc = q + ((size_t)(rrow * 256 + i0 + row) * 512 + head * 64 + ch);
      const bf16* ksrc = kk + ((size_t)(rrow * 256 + j0 + row) * 512 + head * 64 + ch);
      *(uint4*)&Qs[row * 72 + ch] = *(const uint4*)qsrc;
      *(uint4*)&Qs[row * 72 + ch + 8] = *(const uint4*)(qsrc + 8);
      *(uint4*)&Ks[row * 72 + ch] = *(const uint4*)ksrc;
      *(uint4*)&Ks[row * 72 + ch + 8] = *(const uint4*)(ksrc + 8);
    }
    __syncthreads();
#pragma unroll
    for (int ks = 0; ks < 2; ks++) {
      bf16x8 af = *(const bf16x8*)&Qs[(wv * 16 + m16) * 72 + ks * 32 + kq * 8];
      bf16x8 bfr[4];
#pragma unroll
      for (int jt = 0; jt < 4; jt++)
        bfr[jt] = *(const bf16x8*)&Ks[(jt * 16 + m16) * 72 + ks * 32 + kq * 8];
#pragma unroll
      for (int jt = 0; jt < 4; jt++) acc[jt] = MFMA16(af, bfr[jt], acc[jt]);
    }
  }
  const float sc = 1.f / 128.f;  // dh^-0.5 * H^-0.5
#pragma unroll
  for (int jt = 0; jt < 4; jt++)
#pragma unroll
    for (int r = 0; r < 4; r++)
      slice[(size_t)(i0 + wv * 16 + kq * 4 + r) * 256 + j0 + jt * 16 + m16] = acc[jt][r] * sc;
}

// ---------------------------------------------------------------- pair bias: LN + @W_pair -> dp slice 0
__global__ void __launch_bounds__(256) k_pb(const float* __restrict__ pb,
                                            const float* __restrict__ g,
                                            const float* __restrict__ bb,
                                            const float* __restrict__ Wp,
                                            float* __restrict__ dots) {
  __shared__ float sn[4][128];
  const int tid = threadIdx.x, lane = tid & 63, wv = tid >> 6;
  const size_t ij = (size_t)blockIdx.x * 4 + wv;
  const float2 xv = *(const float2*)(pb + ij * 128 + lane * 2);

  float s = xv.x + xv.y;
#pragma unroll
  for (int o = 1; o < 64; o <<= 1) s += __shfl_xor(s, o);
  const float mu = s * (1.f / 128.f);
  const float d0 = xv.x - mu, d1 = xv.y - mu;
  float s2 = d0 * d0 + d1 * d1;
#pragma unroll
  for (int o = 1; o < 64; o <<= 1) s2 += __shfl_xor(s2, o);
  const float inv = rsqrtf(s2 * (1.f / 128.f) + 1e-5f);

  sn[wv][lane * 2 + 0] = d0 * inv * g[lane * 2 + 0] + bb[lane * 2 + 0];
  sn[wv][lane * 2 + 1] = d1 * inv * g[lane * 2 + 1] + bb[lane * 2 + 1];

  const int h = lane & 7, gp = lane >> 3;
  float a = 0.f;
#pragma unroll
  for (int p0 = 0; p0 < 16; p0++) {
    const int p = gp * 16 + p0;
    a += sn[wv][p] * Wp[p * 8 + h];
  }
  a += __shfl_xor(a, 8);
  a += __shfl_xor(a, 16);
  a += __shfl_xor(a, 32);
  if (lane < 8) dots[(size_t)h * 65536 + ij] += a;
}

// ---------------------------------------------------------------- softmax summing 8 split-K slices -> bf16 P
__global__ void __launch_bounds__(256) k_softmax8(const float* __restrict__ dp,
                                                  bf16* __restrict__ P) {
  __shared__ float red[4];
  const int i = blockIdx.x, head = blockIdx.y, t = threadIdx.x;
  const size_t base = (size_t)head * 65536 + i * 256 + t;
  float lg = 0.f;
#pragma unroll
  for (int s = 0; s < 8; s++) lg += dp[(size_t)s * 524288 + base];
  const float e = __expf(lg);
  float s = e;
#pragma unroll
  for (int o = 1; o < 64; o <<= 1) s += __shfl_xor(s, o);
  if ((t & 63) == 0) red[t >> 6] = s;
  __syncthreads();
  const float S = red[0] + red[1] + red[2] + red[3];
  P[base] = __float2bfloat16(e / S);
}

// ---------------------------------------------------------------- height PV, atomic-free -> Oh (h-major)
__global__ void __launch_bounds__(256, 2)
k_h_pv_o(const bf16* __restrict__ P, const bf16* __restrict__ v, bf16* __restrict__ Oh) {
  __shared__ __align__(16) bf16 Vt[64 * 256];
  const int r = blockIdx.x, head = blockIdx.y;
  const int tid = threadIdx.x, lane = tid & 63, wv = tid >> 6;
  const int m16 = lane & 15, kq = lane >> 4;

  {
    const bf16* src = v + ((size_t)(r * 256 + tid) * 512 + head * 64);
    uint4 rr[8];
#pragma unroll
    for (int c = 0; c < 8; c++) rr[c] = ((const uint4*)src)[c];
    const int jl = tid & 7, jh = tid >> 3;
#pragma unroll
    for (int c = 0; c < 8; c++) {
      const bf16* e = (const bf16*)&rr[c];
#pragma unroll
      for (int t = 0; t < 8; t++) {
        const int d = c * 8 + t;
        Vt[d * 256 + ((jh ^ (d & 7)) << 3) + jl] = e[t];
      }
    }
  }

  const bf16* Pb = P + (size_t)head * 65536;
  const int i0 = wv * 64;
  auto loadP = [&](int ks, bf16x8 pf[4]) {
#pragma unroll
    for (int it = 0; it < 4; it++)
      pf[it] = *(const bf16x8*)(Pb + (size_t)(i0 + it * 16 + m16) * 256 + ks * 32 + kq * 8);
  };
  bf16x8 pcur[4];
  loadP(0, pcur);
  __syncthreads();

  f32x4 acc[4][4];
#pragma unroll
  for (int a = 0; a < 4; a++)
#pragma unroll
    for (int b = 0; b < 4; b++) acc[a][b] = (f32x4){0.f, 0.f, 0.f, 0.f};

#pragma unroll 1
  for (int ks = 0; ks < 8; ks++) {
    bf16x8 pnext[4];
    if (ks < 7) loadP(ks + 1, pnext);
    bf16x8 vf[4];
#pragma unroll
    for (int dt = 0; dt < 4; dt++)
      vf[dt] = *(const bf16x8*)&Vt[(dt * 16 + m16) * 256 + (((ks * 4 + kq) ^ (m16 & 7)) << 3)];
#pragma unroll
    for (int it = 0; it < 4; it++)
#pragma unroll
      for (int dt = 0; dt < 4; dt++) acc[it][dt] = MFMA16(pcur[it], vf[dt], acc[it][dt]);
    if (ks < 7) {
#pragma unroll
      for (int it = 0; it < 4; it++) pcur[it] = pnext[it];
    }
  }
#pragma unroll
  for (int it = 0; it < 4; it++)
#pragma unroll
    for (int dt = 0; dt < 4; dt++)
#pragma unroll
      for (int r2 = 0; r2 < 4; r2++) {
        const int i = i0 + it * 16 + kq * 4 + r2;  // w position
        Oh[((size_t)(r * 256 + i)) * 512 + head * 64 + dt * 16 + m16] =
            __float2bfloat16(acc[it][dt][r2]);
      }
}

// ---------------------------------------------------------------- final fused projection
// out[n] = 0.5*(Ow@Wout_w + Oh@Wout_h)[n] + 0.5*(bw+bh); n = h*256+w (h-major).
// Ow is w-major: its row for out-row n is ((n&255)<<8)|(n>>8).
__global__ void __launch_bounds__(256) k_outproj(const bf16* __restrict__ Ow,
                                                 const bf16* __restrict__ Oh,
                                                 const bf16* __restrict__ Wow,  // [64][512]
                                                 const bf16* __restrict__ Woh,
                                                 const float* __restrict__ bw,
                                                 const float* __restrict__ bh,
                                                 float* __restrict__ out) {
  const int tid = threadIdx.x, lane = tid & 63, wv = tid >> 6;
  const int m16 = lane & 15, kq = lane >> 4;
  const int nA = blockIdx.x * 64 + wv * 16 + m16;
  const int wA = ((nA & 255) << 8) | (nA >> 8);  // w-major remap for Ow

  const bf16* aw = Ow + (size_t)wA * 512 + kq * 8;
  const bf16* ah = Oh + (size_t)nA * 512 + kq * 8;

  f32x4 acc[4];
#pragma unroll
  for (int ct = 0; ct < 4; ct++) acc[ct] = (f32x4){0.f, 0.f, 0.f, 0.f};

#pragma unroll 1
  for (int kc = 0; kc < 16; kc++) {
    const bf16x8 afw = *(const bf16x8*)(aw + kc * 32);
    const bf16x8 afh = *(const bf16x8*)(ah + kc * 32);
#pragma unroll
    for (int ct = 0; ct < 4; ct++) {
      const bf16x8 bfw = *(const bf16x8*)(Wow + (size_t)(ct * 16 + m16) * 512 + kc * 32 + kq * 8);
      const bf16x8 bfh = *(const bf16x8*)(Woh + (size_t)(ct * 16 + m16) * 512 + kc * 32 + kq * 8);
      acc[ct] = MFMA16(afw, bfw, acc[ct]);
      acc[ct] = MFMA16(afh, bfh, acc[ct]);
    }
  }
  const int n0 = blockIdx.x * 64 + wv * 16 + kq * 4;
#pragma unroll
  for (int ct = 0; ct < 4; ct++) {
    const int c = ct * 16 + m16;
    const float bias = 0.5f * (bw[c] + bh[c]);
#pragma unroll
    for (int r = 0; r < 4; r++)
      out[(size_t)(n0 + r) * 64 + c] = 0.5f * acc[ct][r] + bias;
  }
}

// ================================================================ launch
extern "C" void kernel_launch(void* const* d_in, const int* in_sizes, int n_in,
                              void* d_out, int out_size, void* d_ws, size_t ws_size,
                              hipStream_t stream) {
  const float* x      = (const float*)d_in[0];
  const float* pair   = (const float*)d_in[1];
  const float* Wq_w   = (const float*)d_in[2];
  const float* Wkv_w  = (const float*)d_in[3];
  const float* Wout_w = (const float*)d_in[4];
  const float* bout_w = (const float*)d_in[5];
  const float* Wq_h   = (const float*)d_in[6];
  const float* Wkv_h  = (const float*)d_in[7];
  const float* Wout_h = (const float*)d_in[8];
  const float* bout_h = (const float*)d_in[9];
  const float* ln_g   = (const float*)d_in[10];
  const float* ln_b   = (const float*)d_in[11];
  const float* W_pair = (const float*)d_in[12];
  float* out = (float*)d_out;

  char* ws = (char*)d_ws;
  bf16* R0 = (bf16*)ws;                     // width Ow (w-major)
  bf16* R1 = (bf16*)(ws + 67108864);        // height q2 -> height v
  bf16* R2 = (bf16*)(ws + 134217728);       // height k2 -> Oh
  bf16* Wt = (bf16*)(ws + 201326592);       // 384K
  bf16* P  = (bf16*)(ws + 201326592 + 393216);    // 1M
  bf16* Wo_w = (bf16*)(ws + 201326592 + 1441792); // 64K
  bf16* Wo_h = Wo_w + 32768;                      // 64K
  float* dp = out;                          // d_out doubles as split-K scratch (16MB exact)

  // -------- width attention phase (fully fused QKV + attention) --------
  k_wt1<<<384, 256, 0, stream>>>(Wq_w, Wkv_w, Wt);
  k_wo<<<256, 256, 0, stream>>>(Wout_w, Wout_h, Wo_w, Wo_h);
  k_width_fused<<<dim3(WW, NHEADS), 256, 0, stream>>>(x, Wt, R0);

  // -------- height attention phase (h-major) --------
  k_wt1<<<384, 256, 0, stream>>>(Wq_h, Wkv_h, Wt);
  k_qkv_mfma<<<1024, 256, 0, stream>>>(x, Wt, R1, R2, R1, 0, 0, 8);   // q2->R1, k2->R2
  k_dots_s<<<dim3(16, NHEADS, 8), 256, 0, stream>>>(R1, R2, dp);
  k_qkv_mfma<<<1024, 256, 0, stream>>>(x, Wt, R1, R2, R1, 0, 8, 12);  // v->R1 (q2 dead)
  k_pb<<<65536 / 4, 256, 0, stream>>>(pair, ln_g, ln_b, W_pair, dp);  // into slice 0
  k_softmax8<<<dim3(256, NHEADS), 256, 0, stream>>>(dp, P);
  k_h_pv_o<<<dim3(HH, NHEADS), 256, 0, stream>>>(P, R1, R2);          // Oh over k2

  // -------- final fused projection (sole writer of out) --------
  k_outproj<<<1024, 256, 0, stream>>>(R0, R2, Wo_w, Wo_h, bout_w, bout_h, out);
}

// Round 6
// 576.288 us; speedup vs baseline: 1.3986x; 1.3986x over previous
//
#include <hip/hip_runtime.h>
#include <hip/hip_bf16.h>

typedef __hip_bfloat16 bf16;
typedef __attribute__((ext_vector_type(8))) short bf16x8;
typedef __attribute__((ext_vector_type(4))) float f32x4;

#define MFMA16(a, b, c) __builtin_amdgcn_mfma_f32_16x16x32_bf16(a, b, c, 0, 0, 0)

// Problem constants (B=1)
#define HH 256
#define WW 256
#define NHEADS 8
#define NROWS 65536

// ws layout:
//   R0 @ 0          (67108864): width Ow (w-major) -- written by fused width kernel
//   R1 @ 67108864   (67108864): height q2 -> height v
//   R2 @ 134217728  (67108864): height k2 -> Oh (h-major)
//   R3 @ 201326592  (2097152):  Wt (384K) @+0 | P bf16 (1M) @+393216 | Wo_w/Wo_h @+1441792
//   d_out doubles as split-K dots scratch dp (8 x 2MB) before k_outproj overwrites it.
//
// LESSON (R4/R5): on this toolchain __launch_bounds__(256, N) caps VGPRs at ~256/N,
// NOT 512/N -- (256,2) -> 128 VGPR (R3, no spill); (256,3) -> 84 VGPR, which spilled
// acc[4][4]+qf to scratch and produced 1.6 GB/dispatch of scratch traffic (375 us).
// Never declare N>=3 for register-heavy kernels. Occupancy > 2 blocks/CU must come
// from LDS sizing with (256,2), letting the allocator keep 128 VGPRs.
//
// MFMA fragment conventions (verified m89/m91/m120):
//   A-frag: lane l holds A[m = l&15][k = (l>>4)*8 + t], t=0..7
//   B-frag: lane l holds B[n = l&15][k = (l>>4)*8 + t]
//   C/D   : lane l, reg r -> (col = l&15, row = (l>>4)*4 + r)
//   D[m][n] = sum_k A[m][k]*B[n][k]

__device__ __forceinline__ bf16x8 cvt8(const float* f) {
  bf16x8 r;
  bf16* h = (bf16*)&r;
#pragma unroll
  for (int i = 0; i < 8; i++) h[i] = __float2bfloat16(f[i]);
  return r;
}

// ---------------------------------------------------------------- Wq|Wkv transpose -> bf16 [1536][64]
__global__ void __launch_bounds__(256) k_wt1(const float* __restrict__ Wq,
                                             const float* __restrict__ Wkv,
                                             bf16* __restrict__ Wt) {
  const int idx = blockIdx.x * 256 + threadIdx.x;  // [0, 98304)
  const int k = idx / 1536, c = idx - k * 1536;
  const float val = (c < 512) ? Wq[k * 512 + c] : Wkv[k * 1024 + (c - 512)];
  Wt[(size_t)c * 64 + k] = __float2bfloat16(val);
}

// ---------------------------------------------------------------- Wout transpose -> bf16 [64][512]
__global__ void __launch_bounds__(256) k_wo(const float* __restrict__ Wout_w,
                                            const float* __restrict__ Wout_h,
                                            bf16* __restrict__ Wo_w,
                                            bf16* __restrict__ Wo_h) {
  int idx = blockIdx.x * 256 + threadIdx.x;  // [0, 65536)
  const float* W = Wout_w;
  bf16* dst = Wo_w;
  if (idx >= 32768) { idx -= 32768; W = Wout_h; dst = Wo_h; }
  const int c = idx >> 9, d = idx & 511;
  dst[idx] = __float2bfloat16(W[d * 64 + c]);  // Wo[c][d] = Wout[d][c]
}

// ---------------------------------------------------------------- QKV via MFMA (height phase)
__global__ void __launch_bounds__(256) k_qkv_mfma(const float* __restrict__ x,
                                                  const bf16* __restrict__ Wt,
                                                  bf16* __restrict__ d0,
                                                  bf16* __restrict__ d1,
                                                  bf16* __restrict__ d2,
                                                  int swap, int cg_lo, int cg_hi) {
  __shared__ __align__(16) bf16 Cs[64 * 136];  // 17408 B
  const int tid = threadIdx.x, lane = tid & 63, wv = tid >> 6;
  const int m16 = lane & 15, kq = lane >> 4;
  const int rowA = blockIdx.x * 64 + wv * 16 + m16;

  const float* xr = x + (size_t)rowA * 64;
  float xf[8];
  bf16x8 af[2];
  *(float4*)&xf[0] = *(const float4*)(xr + kq * 8);
  *(float4*)&xf[4] = *(const float4*)(xr + kq * 8 + 4);
  af[0] = cvt8(xf);
  *(float4*)&xf[0] = *(const float4*)(xr + 32 + kq * 8);
  *(float4*)&xf[4] = *(const float4*)(xr + 32 + kq * 8 + 4);
  af[1] = cvt8(xf);

  size_t wrow[4];
#pragma unroll
  for (int s = 0; s < 4; s++) {
    const int row = (s * 256 + tid) >> 4;
    const int rc = blockIdx.x * 64 + row;
    const int rr = swap ? (((rc & 255) << 8) | (rc >> 8)) : rc;
    wrow[s] = (size_t)rr * 512;
  }
  const int ccol = (tid & 15) * 8;
  const int lrow0 = wv * 16 + kq * 4;

#pragma unroll 1
  for (int cg = cg_lo; cg < cg_hi; cg++) {
    bf16* dst = (cg < 4) ? d0 : (cg < 8) ? d1 : d2;
    const int cbase = (cg & 3) * 128;
#pragma unroll
    for (int ct = 0; ct < 8; ct++) {
      const bf16* wp = Wt + (size_t)(cg * 128 + ct * 16 + m16) * 64 + kq * 8;
      const bf16x8 b0 = *(const bf16x8*)wp;
      const bf16x8 b1 = *(const bf16x8*)(wp + 32);
      f32x4 a = (f32x4){0.f, 0.f, 0.f, 0.f};
      a = MFMA16(af[0], b0, a);
      a = MFMA16(af[1], b1, a);
#pragma unroll
      for (int r = 0; r < 4; r++)
        Cs[(lrow0 + r) * 136 + ct * 16 + m16] = __float2bfloat16(a[r]);
    }
    __syncthreads();
#pragma unroll
    for (int s = 0; s < 4; s++) {
      const int row = (s * 256 + tid) >> 4;
      *(uint4*)(dst + wrow[s] + cbase + ccol) = *(const uint4*)&Cs[row * 136 + ccol];
    }
    __syncthreads();
  }
}

// ---------------------------------------------------------------- FUSED width QKV + attention
// Block (w, head), 4 waves, reads x (fp32 input, cache-resident) directly.
// __launch_bounds__(256, 2): VGPR cap 128 (proven no-spill in R3). Occupancy comes
// from LDS: 49152 B -> 3 blocks/CU (12 waves/CU) for latency hiding.
//   Qs [256][64] granule-XOR-swizzled @0      (32 KB) -> Ps (4x5 KB) overlays after qf load
//   Ks [64][64]  granule-XOR-swizzled @32768  ( 8 KB) -- one 64-row QUARTER at a time
//   Vt [64 d][64 j] granule-XOR-swizzled @40960 (8 KB)
// Swizzle: element (row, c) at row*64 + (((c>>3) ^ (row&7))<<3) + (c&7).
// Quarters g=0..3: KV MFMA (wave computes 16 j-rows) -> barrier -> attn (2x32 j) -> barrier.
__global__ void __launch_bounds__(256, 2)
k_width_fused(const float* __restrict__ x, const bf16* __restrict__ Wt,
              bf16* __restrict__ Ow) {
  __shared__ __align__(16) char smem[49152];
  bf16* Qs = (bf16*)smem;
  bf16* Ks = (bf16*)(smem + 32768);
  bf16* Vt = (bf16*)(smem + 40960);
  const int w = blockIdx.x, head = blockIdx.y;
  const int tid = threadIdx.x, lane = tid & 63, wv = tid >> 6;
  bf16* Ps = (bf16*)(smem + wv * 5120);  // overlays Qs (dead after qf load)
  const int m16 = lane & 15, kq = lane >> 4;
  const int i0 = wv * 64;

  // ---- Q phase: this wave's 64 rows (i = h), all 64 head-cols ----
  bf16x8 af[4][2];
#pragma unroll
  for (int mt = 0; mt < 4; mt++) {
    const float* xr = x + ((size_t)((i0 + mt * 16 + m16) * 256 + w)) * 64;
    float xf[8];
    *(float4*)&xf[0] = *(const float4*)(xr + kq * 8);
    *(float4*)&xf[4] = *(const float4*)(xr + kq * 8 + 4);
    af[mt][0] = cvt8(xf);
    *(float4*)&xf[0] = *(const float4*)(xr + 32 + kq * 8);
    *(float4*)&xf[4] = *(const float4*)(xr + 32 + kq * 8 + 4);
    af[mt][1] = cvt8(xf);
  }
#pragma unroll
  for (int nt = 0; nt < 4; nt++) {
    const bf16* wp = Wt + (size_t)(head * 64 + nt * 16 + m16) * 64 + kq * 8;
    const bf16x8 w0 = *(const bf16x8*)wp;
    const bf16x8 w1 = *(const bf16x8*)(wp + 32);
#pragma unroll
    for (int mt = 0; mt < 4; mt++) {
      f32x4 a = (f32x4){0.f, 0.f, 0.f, 0.f};
      a = MFMA16(af[mt][0], w0, a);
      a = MFMA16(af[mt][1], w1, a);
#pragma unroll
      for (int r = 0; r < 4; r++) {
        const int i = i0 + mt * 16 + kq * 4 + r;
        const int d = nt * 16 + m16;
        Qs[i * 64 + (((d >> 3) ^ (i & 7)) << 3) + (d & 7)] = __float2bfloat16(a[r]);
      }
    }
  }
  __syncthreads();
  // qf A-frags from own rows (swizzled read, conflict-free)
  bf16x8 qf[4][2];
#pragma unroll
  for (int it = 0; it < 4; it++)
#pragma unroll
    for (int ks = 0; ks < 2; ks++)
      qf[it][ks] = *(const bf16x8*)&Qs[(i0 + it * 16 + m16) * 64 +
                                       (((ks * 4 + kq) ^ (m16 & 7)) << 3)];

  f32x4 acc[4][4];
#pragma unroll
  for (int a = 0; a < 4; a++)
#pragma unroll
    for (int b = 0; b < 4; b++) acc[a][b] = (f32x4){0.f, 0.f, 0.f, 0.f};
  float rsum[4][4];
#pragma unroll
  for (int a = 0; a < 4; a++)
#pragma unroll
    for (int r = 0; r < 4; r++) rsum[a][r] = 0.f;

#pragma unroll 1
  for (int g = 0; g < 4; g++) {
    // ---- K/V quarter: this wave computes 16 rows (jrow = g*64 + wv*16 + ...) ----
    {
      const int jrow = g * 64 + wv * 16 + m16;
      const float* xr = x + ((size_t)(jrow * 256 + w)) * 64;
      float xf[16];
      *(float4*)&xf[0] = *(const float4*)(xr + kq * 8);
      *(float4*)&xf[4] = *(const float4*)(xr + kq * 8 + 4);
      *(float4*)&xf[8] = *(const float4*)(xr + 32 + kq * 8);
      *(float4*)&xf[12] = *(const float4*)(xr + 32 + kq * 8 + 4);
      const bf16x8 ak0 = cvt8(&xf[0]);
      const bf16x8 ak1 = cvt8(&xf[8]);
#pragma unroll
      for (int nt = 0; nt < 4; nt++) {
        const int d = nt * 16 + m16;
        {  // K -> Ks
          const bf16* wp = Wt + (size_t)(512 + head * 64 + d) * 64 + kq * 8;
          const bf16x8 w0 = *(const bf16x8*)wp;
          const bf16x8 w1 = *(const bf16x8*)(wp + 32);
          f32x4 a = (f32x4){0.f, 0.f, 0.f, 0.f};
          a = MFMA16(ak0, w0, a);
          a = MFMA16(ak1, w1, a);
#pragma unroll
          for (int r = 0; r < 4; r++) {
            const int jl = wv * 16 + kq * 4 + r;  // local row in quarter
            Ks[jl * 64 + (((d >> 3) ^ (jl & 7)) << 3) + (d & 7)] = __float2bfloat16(a[r]);
          }
        }
        {  // V -> Vt (transposed), 4 consecutive j packed 8 B
          const bf16* wp = Wt + (size_t)(1024 + head * 64 + d) * 64 + kq * 8;
          const bf16x8 w0 = *(const bf16x8*)wp;
          const bf16x8 w1 = *(const bf16x8*)(wp + 32);
          f32x4 a = (f32x4){0.f, 0.f, 0.f, 0.f};
          a = MFMA16(ak0, w0, a);
          a = MFMA16(ak1, w1, a);
          const int jb = wv * 16 + kq * 4;
          bf16 tmp[4];
#pragma unroll
          for (int r = 0; r < 4; r++) tmp[r] = __float2bfloat16(a[r]);
          *(uint2*)&Vt[d * 64 + (((jb >> 3) ^ (d & 7)) << 3) + (jb & 7)] =
              *(const uint2*)tmp;
        }
      }
    }
    __syncthreads();
    // ---- attention over this quarter's 64 j (2 chunks of 32) ----
#pragma unroll
    for (int jcl = 0; jcl < 2; jcl++) {
      bf16x8 kf[2][2];
#pragma unroll
      for (int jt = 0; jt < 2; jt++) {
        const int j = jcl * 32 + jt * 16 + m16;  // local row in quarter
#pragma unroll
        for (int ks = 0; ks < 2; ks++)
          kf[jt][ks] = *(const bf16x8*)&Ks[j * 64 + (((ks * 4 + kq) ^ (j & 7)) << 3)];
      }
#pragma unroll
      for (int it = 0; it < 4; it++)
#pragma unroll
        for (int jt = 0; jt < 2; jt++) {
          f32x4 s = (f32x4){0.f, 0.f, 0.f, 0.f};
          s = MFMA16(qf[it][0], kf[jt][0], s);
          s = MFMA16(qf[it][1], kf[jt][1], s);
#pragma unroll
          for (int r = 0; r < 4; r++) {
            float p = __expf(s[r] * 0.125f);
            rsum[it][r] += p;
            Ps[(it * 16 + kq * 4 + r) * 40 + jt * 16 + m16] = __float2bfloat16(p);
          }
        }
      bf16x8 pf[4], vf[4];
#pragma unroll
      for (int it = 0; it < 4; it++)
        pf[it] = *(const bf16x8*)&Ps[(it * 16 + m16) * 40 + kq * 8];
#pragma unroll
      for (int dt = 0; dt < 4; dt++)
        vf[dt] = *(const bf16x8*)&Vt[(dt * 16 + m16) * 64 +
                                     (((jcl * 4 + kq) ^ (m16 & 7)) << 3)];
#pragma unroll
      for (int it = 0; it < 4; it++)
#pragma unroll
        for (int dt = 0; dt < 4; dt++) acc[it][dt] = MFMA16(pf[it], vf[dt], acc[it][dt]);
    }
    __syncthreads();
  }

#pragma unroll
  for (int it = 0; it < 4; it++)
#pragma unroll
    for (int r = 0; r < 4; r++) {
      float s = rsum[it][r];
      s += __shfl_xor(s, 1); s += __shfl_xor(s, 2);
      s += __shfl_xor(s, 4); s += __shfl_xor(s, 8);
      rsum[it][r] = 1.f / s;
    }
#pragma unroll
  for (int it = 0; it < 4; it++)
#pragma unroll
    for (int dt = 0; dt < 4; dt++)
#pragma unroll
      for (int r = 0; r < 4; r++) {
        const int i = i0 + it * 16 + kq * 4 + r;  // = h
        Ow[((size_t)(w * 256 + i)) * 512 + head * 64 + dt * 16 + m16] =
            __float2bfloat16(acc[it][dt][r] * rsum[it][r]);
      }
}

// ---------------------------------------------------------------- height tied dots, split-K, plain stores
__global__ void __launch_bounds__(256, 2)
k_dots_s(const bf16* __restrict__ q, const bf16* __restrict__ kk, float* __restrict__ dp) {
  __shared__ __align__(16) bf16 Qs[64 * 72];
  __shared__ __align__(16) bf16 Ks[64 * 72];
  const int tile = blockIdx.x, head = blockIdx.y, rc = blockIdx.z;
  const int i0 = (tile >> 2) * 64, j0 = (tile & 3) * 64;
  const int tid = threadIdx.x, lane = tid & 63, wv = tid >> 6;
  const int m16 = lane & 15, kq = lane >> 4;
  float* slice = dp + (size_t)rc * 524288 + (size_t)head * 65536;

  f32x4 acc[4];
#pragma unroll
  for (int b = 0; b < 4; b++) acc[b] = (f32x4){0.f, 0.f, 0.f, 0.f};

  const int row = tid >> 2, ch = (tid & 3) * 16;
#pragma unroll 1
  for (int rr = 0; rr < 32; rr++) {
    const int rrow = rc * 32 + rr;
    __syncthreads();
    {
      const bf16* qsrc = q + ((size_t)(rrow * 256 + i0 + row) * 512 + head * 64 + ch);
      const bf16* ksrc = kk + ((size_t)(rrow * 256 + j0 + row) * 512 + head * 64 + ch);
      *(uint4*)&Qs[row * 72 + ch] = *(const uint4*)qsrc;
      *(uint4*)&Qs[row * 72 + ch + 8] = *(const uint4*)(qsrc + 8);
      *(uint4*)&Ks[row * 72 + ch] = *(const uint4*)ksrc;
      *(uint4*)&Ks[row * 72 + ch + 8] = *(const uint4*)(ksrc + 8);
    }
    __syncthreads();
#pragma unroll
    for (int ks = 0; ks < 2; ks++) {
      bf16x8 af = *(const bf16x8*)&Qs[(wv * 16 + m16) * 72 + ks * 32 + kq * 8];
      bf16x8 bfr[4];
#pragma unroll
      for (int jt = 0; jt < 4; jt++)
        bfr[jt] = *(const bf16x8*)&Ks[(jt * 16 + m16) * 72 + ks * 32 + kq * 8];
#pragma unroll
      for (int jt = 0; jt < 4; jt++) acc[jt] = MFMA16(af, bfr[jt], acc[jt]);
    }
  }
  const float sc = 1.f / 128.f;  // dh^-0.5 * H^-0.5
#pragma unroll
  for (int jt = 0; jt < 4; jt++)
#pragma unroll
    for (int r = 0; r < 4; r++)
      slice[(size_t)(i0 + wv * 16 + kq * 4 + r) * 256 + j0 + jt * 16 + m16] = acc[jt][r] * sc;
}

// ---------------------------------------------------------------- pair bias: LN + @W_pair -> dp slice 0
__global__ void __launch_bounds__(256) k_pb(const float* __restrict__ pb,
                                            const float* __restrict__ g,
                                            const float* __restrict__ bb,
                                            const float* __restrict__ Wp,
                                            float* __restrict__ dots) {
  __shared__ float sn[4][128];
  const int tid = threadIdx.x, lane = tid & 63, wv = tid >> 6;
  const size_t ij = (size_t)blockIdx.x * 4 + wv;
  const float2 xv = *(const float2*)(pb + ij * 128 + lane * 2);

  float s = xv.x + xv.y;
#pragma unroll
  for (int o = 1; o < 64; o <<= 1) s += __shfl_xor(s, o);
  const float mu = s * (1.f / 128.f);
  const float d0 = xv.x - mu, d1 = xv.y - mu;
  float s2 = d0 * d0 + d1 * d1;
#pragma unroll
  for (int o = 1; o < 64; o <<= 1) s2 += __shfl_xor(s2, o);
  const float inv = rsqrtf(s2 * (1.f / 128.f) + 1e-5f);

  sn[wv][lane * 2 + 0] = d0 * inv * g[lane * 2 + 0] + bb[lane * 2 + 0];
  sn[wv][lane * 2 + 1] = d1 * inv * g[lane * 2 + 1] + bb[lane * 2 + 1];

  const int h = lane & 7, gp = lane >> 3;
  float a = 0.f;
#pragma unroll
  for (int p0 = 0; p0 < 16; p0++) {
    const int p = gp * 16 + p0;
    a += sn[wv][p] * Wp[p * 8 + h];
  }
  a += __shfl_xor(a, 8);
  a += __shfl_xor(a, 16);
  a += __shfl_xor(a, 32);
  if (lane < 8) dots[(size_t)h * 65536 + ij] += a;
}

// ---------------------------------------------------------------- softmax summing 8 split-K slices -> bf16 P
__global__ void __launch_bounds__(256) k_softmax8(const float* __restrict__ dp,
                                                  bf16* __restrict__ P) {
  __shared__ float red[4];
  const int i = blockIdx.x, head = blockIdx.y, t = threadIdx.x;
  const size_t base = (size_t)head * 65536 + i * 256 + t;
  float lg = 0.f;
#pragma unroll
  for (int s = 0; s < 8; s++) lg += dp[(size_t)s * 524288 + base];
  const float e = __expf(lg);
  float s = e;
#pragma unroll
  for (int o = 1; o < 64; o <<= 1) s += __shfl_xor(s, o);
  if ((t & 63) == 0) red[t >> 6] = s;
  __syncthreads();
  const float S = red[0] + red[1] + red[2] + red[3];
  P[base] = __float2bfloat16(e / S);
}

// ---------------------------------------------------------------- height PV, atomic-free -> Oh (h-major)
__global__ void __launch_bounds__(256, 2)
k_h_pv_o(const bf16* __restrict__ P, const bf16* __restrict__ v, bf16* __restrict__ Oh) {
  __shared__ __align__(16) bf16 Vt[64 * 256];
  const int r = blockIdx.x, head = blockIdx.y;
  const int tid = threadIdx.x, lane = tid & 63, wv = tid >> 6;
  const int m16 = lane & 15, kq = lane >> 4;

  {
    const bf16* src = v + ((size_t)(r * 256 + tid) * 512 + head * 64);
    uint4 rr[8];
#pragma unroll
    for (int c = 0; c < 8; c++) rr[c] = ((const uint4*)src)[c];
    const int jl = tid & 7, jh = tid >> 3;
#pragma unroll
    for (int c = 0; c < 8; c++) {
      const bf16* e = (const bf16*)&rr[c];
#pragma unroll
      for (int t = 0; t < 8; t++) {
        const int d = c * 8 + t;
        Vt[d * 256 + ((jh ^ (d & 7)) << 3) + jl] = e[t];
      }
    }
  }

  const bf16* Pb = P + (size_t)head * 65536;
  const int i0 = wv * 64;
  auto loadP = [&](int ks, bf16x8 pf[4]) {
#pragma unroll
    for (int it = 0; it < 4; it++)
      pf[it] = *(const bf16x8*)(Pb + (size_t)(i0 + it * 16 + m16) * 256 + ks * 32 + kq * 8);
  };
  bf16x8 pcur[4];
  loadP(0, pcur);
  __syncthreads();

  f32x4 acc[4][4];
#pragma unroll
  for (int a = 0; a < 4; a++)
#pragma unroll
    for (int b = 0; b < 4; b++) acc[a][b] = (f32x4){0.f, 0.f, 0.f, 0.f};

#pragma unroll 1
  for (int ks = 0; ks < 8; ks++) {
    bf16x8 pnext[4];
    if (ks < 7) loadP(ks + 1, pnext);
    bf16x8 vf[4];
#pragma unroll
    for (int dt = 0; dt < 4; dt++)
      vf[dt] = *(const bf16x8*)&Vt[(dt * 16 + m16) * 256 + (((ks * 4 + kq) ^ (m16 & 7)) << 3)];
#pragma unroll
    for (int it = 0; it < 4; it++)
#pragma unroll
      for (int dt = 0; dt < 4; dt++) acc[it][dt] = MFMA16(pcur[it], vf[dt], acc[it][dt]);
    if (ks < 7) {
#pragma unroll
      for (int it = 0; it < 4; it++) pcur[it] = pnext[it];
    }
  }
#pragma unroll
  for (int it = 0; it < 4; it++)
#pragma unroll
    for (int dt = 0; dt < 4; dt++)
#pragma unroll
      for (int r2 = 0; r2 < 4; r2++) {
        const int i = i0 + it * 16 + kq * 4 + r2;  // w position
        Oh[((size_t)(r * 256 + i)) * 512 + head * 64 + dt * 16 + m16] =
            __float2bfloat16(acc[it][dt][r2]);
      }
}

// ---------------------------------------------------------------- final fused projection
// out[n] = 0.5*(Ow@Wout_w + Oh@Wout_h)[n] + 0.5*(bw+bh); n = h*256+w (h-major).
// Ow is w-major: its row for out-row n is ((n&255)<<8)|(n>>8).
__global__ void __launch_bounds__(256) k_outproj(const bf16* __restrict__ Ow,
                                                 const bf16* __restrict__ Oh,
                                                 const bf16* __restrict__ Wow,  // [64][512]
                                                 const bf16* __restrict__ Woh,
                                                 const float* __restrict__ bw,
                                                 const float* __restrict__ bh,
                                                 float* __restrict__ out) {
  const int tid = threadIdx.x, lane = tid & 63, wv = tid >> 6;
  const int m16 = lane & 15, kq = lane >> 4;
  const int nA = blockIdx.x * 64 + wv * 16 + m16;
  const int wA = ((nA & 255) << 8) | (nA >> 8);  // w-major remap for Ow

  const bf16* aw = Ow + (size_t)wA * 512 + kq * 8;
  const bf16* ah = Oh + (size_t)nA * 512 + kq * 8;

  f32x4 acc[4];
#pragma unroll
  for (int ct = 0; ct < 4; ct++) acc[ct] = (f32x4){0.f, 0.f, 0.f, 0.f};

#pragma unroll 1
  for (int kc = 0; kc < 16; kc++) {
    const bf16x8 afw = *(const bf16x8*)(aw + kc * 32);
    const bf16x8 afh = *(const bf16x8*)(ah + kc * 32);
#pragma unroll
    for (int ct = 0; ct < 4; ct++) {
      const bf16x8 bfw = *(const bf16x8*)(Wow + (size_t)(ct * 16 + m16) * 512 + kc * 32 + kq * 8);
      const bf16x8 bfh = *(const bf16x8*)(Woh + (size_t)(ct * 16 + m16) * 512 + kc * 32 + kq * 8);
      acc[ct] = MFMA16(afw, bfw, acc[ct]);
      acc[ct] = MFMA16(afh, bfh, acc[ct]);
    }
  }
  const int n0 = blockIdx.x * 64 + wv * 16 + kq * 4;
#pragma unroll
  for (int ct = 0; ct < 4; ct++) {
    const int c = ct * 16 + m16;
    const float bias = 0.5f * (bw[c] + bh[c]);
#pragma unroll
    for (int r = 0; r < 4; r++)
      out[(size_t)(n0 + r) * 64 + c] = 0.5f * acc[ct][r] + bias;
  }
}

// ================================================================ launch
extern "C" void kernel_launch(void* const* d_in, const int* in_sizes, int n_in,
                              void* d_out, int out_size, void* d_ws, size_t ws_size,
                              hipStream_t stream) {
  const float* x      = (const float*)d_in[0];
  const float* pair   = (const float*)d_in[1];
  const float* Wq_w   = (const float*)d_in[2];
  const float* Wkv_w  = (const float*)d_in[3];
  const float* Wout_w = (const float*)d_in[4];
  const float* bout_w = (const float*)d_in[5];
  const float* Wq_h   = (const float*)d_in[6];
  const float* Wkv_h  = (const float*)d_in[7];
  const float* Wout_h = (const float*)d_in[8];
  const float* bout_h = (const float*)d_in[9];
  const float* ln_g   = (const float*)d_in[10];
  const float* ln_b   = (const float*)d_in[11];
  const float* W_pair = (const float*)d_in[12];
  float* out = (float*)d_out;

  char* ws = (char*)d_ws;
  bf16* R0 = (bf16*)ws;                     // width Ow (w-major)
  bf16* R1 = (bf16*)(ws + 67108864);        // height q2 -> height v
  bf16* R2 = (bf16*)(ws + 134217728);       // height k2 -> Oh
  bf16* Wt = (bf16*)(ws + 201326592);       // 384K
  bf16* P  = (bf16*)(ws + 201326592 + 393216);    // 1M
  bf16* Wo_w = (bf16*)(ws + 201326592 + 1441792); // 64K
  bf16* Wo_h = Wo_w + 32768;                      // 64K
  float* dp = out;                          // d_out doubles as split-K scratch (16MB exact)

  // -------- width attention phase (fully fused QKV + attention) --------
  k_wt1<<<384, 256, 0, stream>>>(Wq_w, Wkv_w, Wt);
  k_wo<<<256, 256, 0, stream>>>(Wout_w, Wout_h, Wo_w, Wo_h);
  k_width_fused<<<dim3(WW, NHEADS), 256, 0, stream>>>(x, Wt, R0);

  // -------- height attention phase (h-major) --------
  k_wt1<<<384, 256, 0, stream>>>(Wq_h, Wkv_h, Wt);
  k_qkv_mfma<<<1024, 256, 0, stream>>>(x, Wt, R1, R2, R1, 0, 0, 8);   // q2->R1, k2->R2
  k_dots_s<<<dim3(16, NHEADS, 8), 256, 0, stream>>>(R1, R2, dp);
  k_qkv_mfma<<<1024, 256, 0, stream>>>(x, Wt, R1, R2, R1, 0, 8, 12);  // v->R1 (q2 dead)
  k_pb<<<65536 / 4, 256, 0, stream>>>(pair, ln_g, ln_b, W_pair, dp);  // into slice 0
  k_softmax8<<<dim3(256, NHEADS), 256, 0, stream>>>(dp, P);
  k_h_pv_o<<<dim3(HH, NHEADS), 256, 0, stream>>>(P, R1, R2);          // Oh over k2

  // -------- final fused projection (sole writer of out) --------
  k_outproj<<<1024, 256, 0, stream>>>(R0, R2, Wo_w, Wo_h, bout_w, bout_h, out);
}

// Round 7
// 526.352 us; speedup vs baseline: 1.5313x; 1.0949x over previous
//
#include <hip/hip_runtime.h>
#include <hip/hip_bf16.h>

typedef __hip_bfloat16 bf16;
typedef __attribute__((ext_vector_type(8))) short bf16x8;
typedef __attribute__((ext_vector_type(4))) float f32x4;

#define MFMA16(a, b, c) __builtin_amdgcn_mfma_f32_16x16x32_bf16(a, b, c, 0, 0, 0)

// Problem constants (B=1)
#define HH 256
#define WW 256
#define NHEADS 8
#define NROWS 65536

// ws layout:
//   R0 @ 0          (67108864): width Ow (w-major) -- written by fused width kernel
//   R1 @ 67108864   : UNUSED (height phase fully fused now)
//   R2 @ 134217728  (67108864): Oh (h-major), written by k_h_pv_f
//   R3 @ 201326592  (2097152):  Wt (384K) @+0 | P bf16 (1M) @+393216 | Wo_w/Wo_h @+1441792
//   d_out doubles as split-K dots scratch dp (8 x 2MB) before k_outproj overwrites it.
//
// LESSONS:
//   (R4/R5) __launch_bounds__(256, N) caps VGPRs at ~256/N on this toolchain --
//     (256,2)->128 ok; (256,3)->84 spilled acc to scratch (1.6 GB/dispatch). Never N>=3
//     for register-heavy kernels.
//   (R6) quarter K/V tiles: 2x barriers + 2x Wt re-reads, occupancy unchanged -> 126->154us.
//     R3 half-tile structure is the proven best width kernel.
//   (R2/R3/R7) the only >10% levers on this pipeline are DELETED BYTES: fusing the QKV
//     projection into its consumer (recompute from cache-resident x) beats any store/
//     load pattern tuning of the ws round trip.
//
// MFMA fragment conventions (verified m89/m91/m120):
//   A-frag: lane l holds A[m = l&15][k = (l>>4)*8 + t], t=0..7
//   B-frag: lane l holds B[n = l&15][k = (l>>4)*8 + t]
//   C/D   : lane l, reg r -> (col = l&15, row = (l>>4)*4 + r)
//   D[m][n] = sum_k A[m][k]*B[n][k]

__device__ __forceinline__ bf16x8 cvt8(const float* f) {
  bf16x8 r;
  bf16* h = (bf16*)&r;
#pragma unroll
  for (int i = 0; i < 8; i++) h[i] = __float2bfloat16(f[i]);
  return r;
}

// ---------------------------------------------------------------- Wq|Wkv transpose -> bf16 [1536][64]
__global__ void __launch_bounds__(256) k_wt1(const float* __restrict__ Wq,
                                             const float* __restrict__ Wkv,
                                             bf16* __restrict__ Wt) {
  const int idx = blockIdx.x * 256 + threadIdx.x;  // [0, 98304)
  const int k = idx / 1536, c = idx - k * 1536;
  const float val = (c < 512) ? Wq[k * 512 + c] : Wkv[k * 1024 + (c - 512)];
  Wt[(size_t)c * 64 + k] = __float2bfloat16(val);
}

// ---------------------------------------------------------------- Wout transpose -> bf16 [64][512]
__global__ void __launch_bounds__(256) k_wo(const float* __restrict__ Wout_w,
                                            const float* __restrict__ Wout_h,
                                            bf16* __restrict__ Wo_w,
                                            bf16* __restrict__ Wo_h) {
  int idx = blockIdx.x * 256 + threadIdx.x;  // [0, 65536)
  const float* W = Wout_w;
  bf16* dst = Wo_w;
  if (idx >= 32768) { idx -= 32768; W = Wout_h; dst = Wo_h; }
  const int c = idx >> 9, d = idx & 511;
  dst[idx] = __float2bfloat16(W[d * 64 + c]);  // Wo[c][d] = Wout[d][c]
}

// ---------------------------------------------------------------- FUSED width QKV + attention
// R3-proven structure (126 us): block (w, head), 4 waves, reads x directly.
// LDS 65536 (2 blocks/CU):
//   Qs [256][64] granule-XOR-swizzled @0      (32 KB) -> Ps (4x5 KB) overlays after qf load
//   Ks [128][64] granule-XOR-swizzled @32768  (16 KB) -- one 128-row HALF at a time
//   Vt [64 d][128 j] granule-XOR-swizzled @49152 (16 KB)
// Swizzle: element (row, c) at row*64 + (((c>>3) ^ (row&7))<<3) + (c&7).
__global__ void __launch_bounds__(256, 2)
k_width_fused(const float* __restrict__ x, const bf16* __restrict__ Wt,
              bf16* __restrict__ Ow) {
  __shared__ __align__(16) char smem[65536];
  bf16* Qs = (bf16*)smem;
  bf16* Ks = (bf16*)(smem + 32768);
  bf16* Vt = (bf16*)(smem + 49152);
  const int w = blockIdx.x, head = blockIdx.y;
  const int tid = threadIdx.x, lane = tid & 63, wv = tid >> 6;
  bf16* Ps = (bf16*)(smem + wv * 5120);  // overlays Qs (dead after qf load)
  const int m16 = lane & 15, kq = lane >> 4;
  const int i0 = wv * 64;

  // ---- Q phase: this wave's 64 rows (i = h), all 64 head-cols ----
  bf16x8 af[4][2];
#pragma unroll
  for (int mt = 0; mt < 4; mt++) {
    const float* xr = x + ((size_t)((i0 + mt * 16 + m16) * 256 + w)) * 64;
    float xf[8];
    *(float4*)&xf[0] = *(const float4*)(xr + kq * 8);
    *(float4*)&xf[4] = *(const float4*)(xr + kq * 8 + 4);
    af[mt][0] = cvt8(xf);
    *(float4*)&xf[0] = *(const float4*)(xr + 32 + kq * 8);
    *(float4*)&xf[4] = *(const float4*)(xr + 32 + kq * 8 + 4);
    af[mt][1] = cvt8(xf);
  }
#pragma unroll
  for (int nt = 0; nt < 4; nt++) {
    const bf16* wp = Wt + (size_t)(head * 64 + nt * 16 + m16) * 64 + kq * 8;
    const bf16x8 w0 = *(const bf16x8*)wp;
    const bf16x8 w1 = *(const bf16x8*)(wp + 32);
#pragma unroll
    for (int mt = 0; mt < 4; mt++) {
      f32x4 a = (f32x4){0.f, 0.f, 0.f, 0.f};
      a = MFMA16(af[mt][0], w0, a);
      a = MFMA16(af[mt][1], w1, a);
#pragma unroll
      for (int r = 0; r < 4; r++) {
        const int i = i0 + mt * 16 + kq * 4 + r;
        const int d = nt * 16 + m16;
        Qs[i * 64 + (((d >> 3) ^ (i & 7)) << 3) + (d & 7)] = __float2bfloat16(a[r]);
      }
    }
  }
  __syncthreads();
  // qf A-frags from own rows (swizzled read, conflict-free)
  bf16x8 qf[4][2];
#pragma unroll
  for (int it = 0; it < 4; it++)
#pragma unroll
    for (int ks = 0; ks < 2; ks++)
      qf[it][ks] = *(const bf16x8*)&Qs[(i0 + it * 16 + m16) * 64 +
                                       (((ks * 4 + kq) ^ (m16 & 7)) << 3)];

  f32x4 acc[4][4];
#pragma unroll
  for (int a = 0; a < 4; a++)
#pragma unroll
    for (int b = 0; b < 4; b++) acc[a][b] = (f32x4){0.f, 0.f, 0.f, 0.f};
  float rsum[4][4];
#pragma unroll
  for (int a = 0; a < 4; a++)
#pragma unroll
    for (int r = 0; r < 4; r++) rsum[a][r] = 0.f;

#pragma unroll 1
  for (int half = 0; half < 2; half++) {
    if (half) __syncthreads();  // all reads of prior half's Ks/Vt done
    // ---- K/V phase: this wave computes 32 rows (local j = wv*32..+32) of this half ----
    bf16x8 afk[2][2];
#pragma unroll
    for (int mt = 0; mt < 2; mt++) {
      const int jrow = half * 128 + wv * 32 + mt * 16 + m16;  // global j (= h)
      const float* xr = x + ((size_t)(jrow * 256 + w)) * 64;
      float xf[8];
      *(float4*)&xf[0] = *(const float4*)(xr + kq * 8);
      *(float4*)&xf[4] = *(const float4*)(xr + kq * 8 + 4);
      afk[mt][0] = cvt8(xf);
      *(float4*)&xf[0] = *(const float4*)(xr + 32 + kq * 8);
      *(float4*)&xf[4] = *(const float4*)(xr + 32 + kq * 8 + 4);
      afk[mt][1] = cvt8(xf);
    }
#pragma unroll
    for (int nt = 0; nt < 4; nt++) {
      const int d = nt * 16 + m16;
      {  // K -> Ks
        const bf16* wp = Wt + (size_t)(512 + head * 64 + d) * 64 + kq * 8;
        const bf16x8 w0 = *(const bf16x8*)wp;
        const bf16x8 w1 = *(const bf16x8*)(wp + 32);
#pragma unroll
        for (int mt = 0; mt < 2; mt++) {
          f32x4 a = (f32x4){0.f, 0.f, 0.f, 0.f};
          a = MFMA16(afk[mt][0], w0, a);
          a = MFMA16(afk[mt][1], w1, a);
#pragma unroll
          for (int r = 0; r < 4; r++) {
            const int jl = wv * 32 + mt * 16 + kq * 4 + r;  // local row in half
            Ks[jl * 64 + (((d >> 3) ^ (jl & 7)) << 3) + (d & 7)] = __float2bfloat16(a[r]);
          }
        }
      }
      {  // V -> Vt (transposed), 4 consecutive j packed as 8 B
        const bf16* wp = Wt + (size_t)(1024 + head * 64 + d) * 64 + kq * 8;
        const bf16x8 w0 = *(const bf16x8*)wp;
        const bf16x8 w1 = *(const bf16x8*)(wp + 32);
#pragma unroll
        for (int mt = 0; mt < 2; mt++) {
          f32x4 a = (f32x4){0.f, 0.f, 0.f, 0.f};
          a = MFMA16(afk[mt][0], w0, a);
          a = MFMA16(afk[mt][1], w1, a);
          const int jb = wv * 32 + mt * 16 + kq * 4;  // local j base (r=0..3)
          bf16 tmp[4];
#pragma unroll
          for (int r = 0; r < 4; r++) tmp[r] = __float2bfloat16(a[r]);
          *(uint2*)&Vt[d * 128 + (((jb >> 3) ^ (d & 7)) << 3) + (jb & 7)] =
              *(const uint2*)tmp;
        }
      }
    }
    __syncthreads();
    // ---- attention over this half's 128 j ----
#pragma unroll 1
    for (int jcl = 0; jcl < 4; jcl++) {
      bf16x8 kf[2][2];
#pragma unroll
      for (int jt = 0; jt < 2; jt++) {
        const int j = jcl * 32 + jt * 16 + m16;  // local row in half
#pragma unroll
        for (int ks = 0; ks < 2; ks++)
          kf[jt][ks] = *(const bf16x8*)&Ks[j * 64 + (((ks * 4 + kq) ^ (j & 7)) << 3)];
      }
#pragma unroll
      for (int it = 0; it < 4; it++)
#pragma unroll
        for (int jt = 0; jt < 2; jt++) {
          f32x4 s = (f32x4){0.f, 0.f, 0.f, 0.f};
          s = MFMA16(qf[it][0], kf[jt][0], s);
          s = MFMA16(qf[it][1], kf[jt][1], s);
#pragma unroll
          for (int r = 0; r < 4; r++) {
            float p = __expf(s[r] * 0.125f);
            rsum[it][r] += p;
            Ps[(it * 16 + kq * 4 + r) * 40 + jt * 16 + m16] = __float2bfloat16(p);
          }
        }
      bf16x8 pf[4], vf[4];
#pragma unroll
      for (int it = 0; it < 4; it++)
        pf[it] = *(const bf16x8*)&Ps[(it * 16 + m16) * 40 + kq * 8];
#pragma unroll
      for (int dt = 0; dt < 4; dt++)
        vf[dt] = *(const bf16x8*)&Vt[(dt * 16 + m16) * 128 +
                                     (((jcl * 4 + kq) ^ (m16 & 7)) << 3)];
#pragma unroll
      for (int it = 0; it < 4; it++)
#pragma unroll
        for (int dt = 0; dt < 4; dt++) acc[it][dt] = MFMA16(pf[it], vf[dt], acc[it][dt]);
    }
  }

#pragma unroll
  for (int it = 0; it < 4; it++)
#pragma unroll
    for (int r = 0; r < 4; r++) {
      float s = rsum[it][r];
      s += __shfl_xor(s, 1); s += __shfl_xor(s, 2);
      s += __shfl_xor(s, 4); s += __shfl_xor(s, 8);
      rsum[it][r] = 1.f / s;
    }
#pragma unroll
  for (int it = 0; it < 4; it++)
#pragma unroll
    for (int dt = 0; dt < 4; dt++)
#pragma unroll
      for (int r = 0; r < 4; r++) {
        const int i = i0 + it * 16 + kq * 4 + r;  // = h
        Ow[((size_t)(w * 256 + i)) * 512 + head * 64 + dt * 16 + m16] =
            __float2bfloat16(acc[it][dt][r] * rsum[it][r]);
      }
}

// ---------------------------------------------------------------- FUSED height tied dots (split-K)
// k_dots_s with the ws staging replaced by on-the-fly Q/K projection from x.
// grid (16 tiles 64x64, 8 heads, 8 rc), block 256 = 4 waves.
// Per rr: each wave projects 16 q-rows and 16 k-rows (x fp32 -> bf16 -> MFMA vs Wt
// head-slices) into Qs/Ks (stride 72, proven layout), then the dots MFMAs as before.
// Deletes the q2/k2 qkv dispatch (128 MB ws write + read).
__global__ void __launch_bounds__(256, 2)
k_dots_f(const float* __restrict__ x, const bf16* __restrict__ Wt, float* __restrict__ dp) {
  __shared__ __align__(16) bf16 Qs[64 * 72];
  __shared__ __align__(16) bf16 Ks[64 * 72];
  const int tile = blockIdx.x, head = blockIdx.y, rc = blockIdx.z;
  const int i0 = (tile >> 2) * 64, j0 = (tile & 3) * 64;
  const int tid = threadIdx.x, lane = tid & 63, wv = tid >> 6;
  const int m16 = lane & 15, kq = lane >> 4;
  float* slice = dp + (size_t)rc * 524288 + (size_t)head * 65536;

  const bf16* WtQ = Wt + (size_t)(head * 64) * 64 + kq * 8;
  const bf16* WtK = Wt + (size_t)(512 + head * 64) * 64 + kq * 8;

  f32x4 acc[4];
#pragma unroll
  for (int b = 0; b < 4; b++) acc[b] = (f32x4){0.f, 0.f, 0.f, 0.f};

  const int lrow = wv * 16 + kq * 4;

#pragma unroll 1
  for (int rr = 0; rr < 32; rr++) {
    const int rbase = (rc * 32 + rr) * 256;
    __syncthreads();  // prior iteration's dots reads done
    {
      // q-rows: x rows rbase + i0 + wv*16 + m16 (contiguous per wave)
      const float* xr = x + (size_t)(rbase + i0 + wv * 16 + m16) * 64;
      float xf[8];
      bf16x8 qa0, qa1, ka0, ka1;
      *(float4*)&xf[0] = *(const float4*)(xr + kq * 8);
      *(float4*)&xf[4] = *(const float4*)(xr + kq * 8 + 4);
      qa0 = cvt8(xf);
      *(float4*)&xf[0] = *(const float4*)(xr + 32 + kq * 8);
      *(float4*)&xf[4] = *(const float4*)(xr + 32 + kq * 8 + 4);
      qa1 = cvt8(xf);
      const float* yr = x + (size_t)(rbase + j0 + wv * 16 + m16) * 64;
      *(float4*)&xf[0] = *(const float4*)(yr + kq * 8);
      *(float4*)&xf[4] = *(const float4*)(yr + kq * 8 + 4);
      ka0 = cvt8(xf);
      *(float4*)&xf[0] = *(const float4*)(yr + 32 + kq * 8);
      *(float4*)&xf[4] = *(const float4*)(yr + 32 + kq * 8 + 4);
      ka1 = cvt8(xf);
#pragma unroll
      for (int nt = 0; nt < 4; nt++) {
        const bf16* wq = WtQ + (size_t)(nt * 16 + m16) * 64;
        f32x4 aq = (f32x4){0.f, 0.f, 0.f, 0.f};
        aq = MFMA16(qa0, *(const bf16x8*)wq, aq);
        aq = MFMA16(qa1, *(const bf16x8*)(wq + 32), aq);
        const bf16* wk = WtK + (size_t)(nt * 16 + m16) * 64;
        f32x4 ak = (f32x4){0.f, 0.f, 0.f, 0.f};
        ak = MFMA16(ka0, *(const bf16x8*)wk, ak);
        ak = MFMA16(ka1, *(const bf16x8*)(wk + 32), ak);
#pragma unroll
        for (int r = 0; r < 4; r++) {
          Qs[(lrow + r) * 72 + nt * 16 + m16] = __float2bfloat16(aq[r]);
          Ks[(lrow + r) * 72 + nt * 16 + m16] = __float2bfloat16(ak[r]);
        }
      }
    }
    __syncthreads();
#pragma unroll
    for (int ks = 0; ks < 2; ks++) {
      bf16x8 af = *(const bf16x8*)&Qs[(wv * 16 + m16) * 72 + ks * 32 + kq * 8];
      bf16x8 bfr[4];
#pragma unroll
      for (int jt = 0; jt < 4; jt++)
        bfr[jt] = *(const bf16x8*)&Ks[(jt * 16 + m16) * 72 + ks * 32 + kq * 8];
#pragma unroll
      for (int jt = 0; jt < 4; jt++) acc[jt] = MFMA16(af, bfr[jt], acc[jt]);
    }
  }
  const float sc = 1.f / 128.f;  // dh^-0.5 * H^-0.5
#pragma unroll
  for (int jt = 0; jt < 4; jt++)
#pragma unroll
    for (int r = 0; r < 4; r++)
      slice[(size_t)(i0 + wv * 16 + kq * 4 + r) * 256 + j0 + jt * 16 + m16] = acc[jt][r] * sc;
}

// ---------------------------------------------------------------- pair bias: LN + @W_pair -> dp slice 0
__global__ void __launch_bounds__(256) k_pb(const float* __restrict__ pb,
                                            const float* __restrict__ g,
                                            const float* __restrict__ bb,
                                            const float* __restrict__ Wp,
                                            float* __restrict__ dots) {
  __shared__ float sn[4][128];
  const int tid = threadIdx.x, lane = tid & 63, wv = tid >> 6;
  const size_t ij = (size_t)blockIdx.x * 4 + wv;
  const float2 xv = *(const float2*)(pb + ij * 128 + lane * 2);

  float s = xv.x + xv.y;
#pragma unroll
  for (int o = 1; o < 64; o <<= 1) s += __shfl_xor(s, o);
  const float mu = s * (1.f / 128.f);
  const float d0 = xv.x - mu, d1 = xv.y - mu;
  float s2 = d0 * d0 + d1 * d1;
#pragma unroll
  for (int o = 1; o < 64; o <<= 1) s2 += __shfl_xor(s2, o);
  const float inv = rsqrtf(s2 * (1.f / 128.f) + 1e-5f);

  sn[wv][lane * 2 + 0] = d0 * inv * g[lane * 2 + 0] + bb[lane * 2 + 0];
  sn[wv][lane * 2 + 1] = d1 * inv * g[lane * 2 + 1] + bb[lane * 2 + 1];

  const int h = lane & 7, gp = lane >> 3;
  float a = 0.f;
#pragma unroll
  for (int p0 = 0; p0 < 16; p0++) {
    const int p = gp * 16 + p0;
    a += sn[wv][p] * Wp[p * 8 + h];
  }
  a += __shfl_xor(a, 8);
  a += __shfl_xor(a, 16);
  a += __shfl_xor(a, 32);
  if (lane < 8) dots[(size_t)h * 65536 + ij] += a;
}

// ---------------------------------------------------------------- softmax summing 8 split-K slices -> bf16 P
__global__ void __launch_bounds__(256) k_softmax8(const float* __restrict__ dp,
                                                  bf16* __restrict__ P) {
  __shared__ float red[4];
  const int i = blockIdx.x, head = blockIdx.y, t = threadIdx.x;
  const size_t base = (size_t)head * 65536 + i * 256 + t;
  float lg = 0.f;
#pragma unroll
  for (int s = 0; s < 8; s++) lg += dp[(size_t)s * 524288 + base];
  const float e = __expf(lg);
  float s = e;
#pragma unroll
  for (int o = 1; o < 64; o <<= 1) s += __shfl_xor(s, o);
  if ((t & 63) == 0) red[t >> 6] = s;
  __syncthreads();
  const float S = red[0] + red[1] + red[2] + red[3];
  P[base] = __float2bfloat16(e / S);
}

// ---------------------------------------------------------------- FUSED height PV -> Oh (h-major)
// k_h_pv_o with the V staging replaced by on-the-fly V projection from x: the MFMA
// C-layout (col=d, row=j) writes the TRANSPOSED swizzled Vt directly (free transpose).
// Deletes the v qkv dispatch (64 MB ws write + read).
__global__ void __launch_bounds__(256, 2)
k_h_pv_f(const bf16* __restrict__ P, const float* __restrict__ x,
         const bf16* __restrict__ Wt, bf16* __restrict__ Oh) {
  __shared__ __align__(16) bf16 Vt[64 * 256];
  const int r = blockIdx.x, head = blockIdx.y;
  const int tid = threadIdx.x, lane = tid & 63, wv = tid >> 6;
  const int m16 = lane & 15, kq = lane >> 4;

  {  // V projection: this wave computes j rows wv*64 .. +64 (x rows r*256 + j)
    const bf16* WtV = Wt + (size_t)(1024 + head * 64) * 64 + kq * 8;
#pragma unroll
    for (int mt = 0; mt < 4; mt++) {
      const int jb16 = wv * 64 + mt * 16;
      const float* xr = x + (size_t)(r * 256 + jb16 + m16) * 64;
      float xf[8];
      bf16x8 a0, a1;
      *(float4*)&xf[0] = *(const float4*)(xr + kq * 8);
      *(float4*)&xf[4] = *(const float4*)(xr + kq * 8 + 4);
      a0 = cvt8(xf);
      *(float4*)&xf[0] = *(const float4*)(xr + 32 + kq * 8);
      *(float4*)&xf[4] = *(const float4*)(xr + 32 + kq * 8 + 4);
      a1 = cvt8(xf);
#pragma unroll
      for (int nt = 0; nt < 4; nt++) {
        const int d = nt * 16 + m16;
        const bf16* wp = WtV + (size_t)(nt * 16 + m16) * 64;
        f32x4 a = (f32x4){0.f, 0.f, 0.f, 0.f};
        a = MFMA16(a0, *(const bf16x8*)wp, a);
        a = MFMA16(a1, *(const bf16x8*)(wp + 32), a);
        const int j = jb16 + kq * 4;  // 4 consecutive j (r2=0..3), same 8-granule
        bf16 tmp[4];
#pragma unroll
        for (int r2 = 0; r2 < 4; r2++) tmp[r2] = __float2bfloat16(a[r2]);
        *(uint2*)&Vt[d * 256 + (((j >> 3) ^ (d & 7)) << 3) + (j & 7)] = *(const uint2*)tmp;
      }
    }
  }

  const bf16* Pb = P + (size_t)head * 65536;
  const int i0 = wv * 64;
  auto loadP = [&](int ks, bf16x8 pf[4]) {
#pragma unroll
    for (int it = 0; it < 4; it++)
      pf[it] = *(const bf16x8*)(Pb + (size_t)(i0 + it * 16 + m16) * 256 + ks * 32 + kq * 8);
  };
  bf16x8 pcur[4];
  loadP(0, pcur);
  __syncthreads();

  f32x4 acc[4][4];
#pragma unroll
  for (int a = 0; a < 4; a++)
#pragma unroll
    for (int b = 0; b < 4; b++) acc[a][b] = (f32x4){0.f, 0.f, 0.f, 0.f};

#pragma unroll 1
  for (int ks = 0; ks < 8; ks++) {
    bf16x8 pnext[4];
    if (ks < 7) loadP(ks + 1, pnext);
    bf16x8 vf[4];
#pragma unroll
    for (int dt = 0; dt < 4; dt++)
      vf[dt] = *(const bf16x8*)&Vt[(dt * 16 + m16) * 256 + (((ks * 4 + kq) ^ (m16 & 7)) << 3)];
#pragma unroll
    for (int it = 0; it < 4; it++)
#pragma unroll
      for (int dt = 0; dt < 4; dt++) acc[it][dt] = MFMA16(pcur[it], vf[dt], acc[it][dt]);
    if (ks < 7) {
#pragma unroll
      for (int it = 0; it < 4; it++) pcur[it] = pnext[it];
    }
  }
#pragma unroll
  for (int it = 0; it < 4; it++)
#pragma unroll
    for (int dt = 0; dt < 4; dt++)
#pragma unroll
      for (int r2 = 0; r2 < 4; r2++) {
        const int i = i0 + it * 16 + kq * 4 + r2;  // w position
        Oh[((size_t)(r * 256 + i)) * 512 + head * 64 + dt * 16 + m16] =
            __float2bfloat16(acc[it][dt][r2]);
      }
}

// ---------------------------------------------------------------- final fused projection
// out[n] = 0.5*(Ow@Wout_w + Oh@Wout_h)[n] + 0.5*(bw+bh); n = h*256+w (h-major).
// Ow is w-major: its row for out-row n is ((n&255)<<8)|(n>>8).
__global__ void __launch_bounds__(256) k_outproj(const bf16* __restrict__ Ow,
                                                 const bf16* __restrict__ Oh,
                                                 const bf16* __restrict__ Wow,  // [64][512]
                                                 const bf16* __restrict__ Woh,
                                                 const float* __restrict__ bw,
                                                 const float* __restrict__ bh,
                                                 float* __restrict__ out) {
  const int tid = threadIdx.x, lane = tid & 63, wv = tid >> 6;
  const int m16 = lane & 15, kq = lane >> 4;
  const int nA = blockIdx.x * 64 + wv * 16 + m16;
  const int wA = ((nA & 255) << 8) | (nA >> 8);  // w-major remap for Ow

  const bf16* aw = Ow + (size_t)wA * 512 + kq * 8;
  const bf16* ah = Oh + (size_t)nA * 512 + kq * 8;

  f32x4 acc[4];
#pragma unroll
  for (int ct = 0; ct < 4; ct++) acc[ct] = (f32x4){0.f, 0.f, 0.f, 0.f};

#pragma unroll 1
  for (int kc = 0; kc < 16; kc++) {
    const bf16x8 afw = *(const bf16x8*)(aw + kc * 32);
    const bf16x8 afh = *(const bf16x8*)(ah + kc * 32);
#pragma unroll
    for (int ct = 0; ct < 4; ct++) {
      const bf16x8 bfw = *(const bf16x8*)(Wow + (size_t)(ct * 16 + m16) * 512 + kc * 32 + kq * 8);
      const bf16x8 bfh = *(const bf16x8*)(Woh + (size_t)(ct * 16 + m16) * 512 + kc * 32 + kq * 8);
      acc[ct] = MFMA16(afw, bfw, acc[ct]);
      acc[ct] = MFMA16(afh, bfh, acc[ct]);
    }
  }
  const int n0 = blockIdx.x * 64 + wv * 16 + kq * 4;
#pragma unroll
  for (int ct = 0; ct < 4; ct++) {
    const int c = ct * 16 + m16;
    const float bias = 0.5f * (bw[c] + bh[c]);
#pragma unroll
    for (int r = 0; r < 4; r++)
      out[(size_t)(n0 + r) * 64 + c] = 0.5f * acc[ct][r] + bias;
  }
}

// ================================================================ launch
extern "C" void kernel_launch(void* const* d_in, const int* in_sizes, int n_in,
                              void* d_out, int out_size, void* d_ws, size_t ws_size,
                              hipStream_t stream) {
  const float* x      = (const float*)d_in[0];
  const float* pair   = (const float*)d_in[1];
  const float* Wq_w   = (const float*)d_in[2];
  const float* Wkv_w  = (const float*)d_in[3];
  const float* Wout_w = (const float*)d_in[4];
  const float* bout_w = (const float*)d_in[5];
  const float* Wq_h   = (const float*)d_in[6];
  const float* Wkv_h  = (const float*)d_in[7];
  const float* Wout_h = (const float*)d_in[8];
  const float* bout_h = (const float*)d_in[9];
  const float* ln_g   = (const float*)d_in[10];
  const float* ln_b   = (const float*)d_in[11];
  const float* W_pair = (const float*)d_in[12];
  float* out = (float*)d_out;

  char* ws = (char*)d_ws;
  bf16* R0 = (bf16*)ws;                     // width Ow (w-major)
  bf16* R2 = (bf16*)(ws + 134217728);       // Oh (h-major)
  bf16* Wt = (bf16*)(ws + 201326592);       // 384K
  bf16* P  = (bf16*)(ws + 201326592 + 393216);    // 1M
  bf16* Wo_w = (bf16*)(ws + 201326592 + 1441792); // 64K
  bf16* Wo_h = Wo_w + 32768;                      // 64K
  float* dp = out;                          // d_out doubles as split-K scratch (16MB exact)

  // -------- width attention phase (fully fused QKV + attention) --------
  k_wt1<<<384, 256, 0, stream>>>(Wq_w, Wkv_w, Wt);
  k_wo<<<256, 256, 0, stream>>>(Wout_w, Wout_h, Wo_w, Wo_h);
  k_width_fused<<<dim3(WW, NHEADS), 256, 0, stream>>>(x, Wt, R0);

  // -------- height attention phase (fully fused projections) --------
  k_wt1<<<384, 256, 0, stream>>>(Wq_h, Wkv_h, Wt);
  k_dots_f<<<dim3(16, NHEADS, 8), 256, 0, stream>>>(x, Wt, dp);
  k_pb<<<65536 / 4, 256, 0, stream>>>(pair, ln_g, ln_b, W_pair, dp);  // into slice 0
  k_softmax8<<<dim3(256, NHEADS), 256, 0, stream>>>(dp, P);
  k_h_pv_f<<<dim3(HH, NHEADS), 256, 0, stream>>>(P, x, Wt, R2);       // Oh

  // -------- final fused projection (sole writer of out) --------
  k_outproj<<<1024, 256, 0, stream>>>(R0, R2, Wo_w, Wo_h, bout_w, bout_h, out);
}